// Round 1
// baseline (2474.091 us; speedup 1.0000x reference)
//
#include <hip/hip_runtime.h>
#include <stdint.h>

namespace {
constexpr int C  = 256;
constexpr int CC = C * C;            // 65536
constexpr int BJORCK = 20;
constexpr int PIT = 10;

// workspace layout in floats
constexpr size_t OFF_U   = 0;                  // 1280
constexpr size_t OFF_S   = 1280;               // 5 (padded)
constexpr size_t OFF_WA  = 2048;               // 5*CC
constexpr size_t OFF_WB  = OFF_WA  + 5 * CC;
constexpr size_t OFF_G   = OFF_WB  + 5 * CC;   // wtw, 5*CC
constexpr size_t OFF_PQ  = OFF_G   + 5 * CC;   // 4*CC
constexpr size_t OFF_C01 = OFF_PQ  + 4 * CC;   // 2*CC
constexpr size_t OFF_M   = OFF_C01 + 2 * CC;   // 8*CC (m1[2][2], m2[2][2])
constexpr size_t OFF_P3  = OFF_M   + 8 * CC;   // 9*CC
constexpr size_t OFF_WC  = OFF_P3  + 9 * CC;   // 9*CC, layout [i][tap][o]
}

// ---------------- threefry2x32 + XLA erfinv (bit-matched to JAX) ----------------
__device__ __forceinline__ void tf_round(uint32_t& x0, uint32_t& x1, int r) {
  x0 += x1; x1 = (x1 << r) | (x1 >> (32 - r)); x1 ^= x0;
}

__device__ __forceinline__ float erfinv_f32(float x) {
  float w = -log1pf(-x * x);
  float p;
  if (w < 5.0f) {
    w -= 2.5f;
    p = 2.81022636e-08f;
    p = fmaf(p, w, 3.43273939e-07f);
    p = fmaf(p, w, -3.5233877e-06f);
    p = fmaf(p, w, -4.39150654e-06f);
    p = fmaf(p, w, 0.00021858087f);
    p = fmaf(p, w, -0.00125372503f);
    p = fmaf(p, w, -0.00417768164f);
    p = fmaf(p, w, 0.246640727f);
    p = fmaf(p, w, 1.50140941f);
  } else {
    w = sqrtf(w) - 3.0f;
    p = -0.000200214257f;
    p = fmaf(p, w, 0.000100950558f);
    p = fmaf(p, w, 0.00134934322f);
    p = fmaf(p, w, -0.00367342844f);
    p = fmaf(p, w, 0.00573950773f);
    p = fmaf(p, w, -0.0076224613f);
    p = fmaf(p, w, 0.00943887047f);
    p = fmaf(p, w, 1.00167406f);
    p = fmaf(p, w, 2.83297682f);
  }
  return p * x;
}

__device__ __forceinline__ float bits_to_normal(uint32_t bits) {
  // jax.random.uniform: bits>>9 | 1.0f bits, -1.0, then *(hi-lo)+lo, clamped at lo
  float f = __uint_as_float((bits >> 9) | 0x3F800000u) - 1.0f;
  const float lo = -0.99999994f;          // nextafter(-1, 0) in fp32
  float uu = fmaxf(lo, f * 2.0f + lo);    // (1.0 - lo) rounds to exactly 2.0f
  return 1.41421356f * erfinv_f32(uu);    // np.float32(sqrt(2)) = 0x3FB504F3
}

__global__ __launch_bounds__(256) void gen_u_kernel(float* __restrict__ u) {
  int i = blockIdx.x * 256 + threadIdx.x;
  if (i >= 640) return;
  // key(1) -> (k0,k1) = (0,1); counts = iota(1280) split into halves (i, 640+i)
  const uint32_t ks0 = 0u, ks1 = 1u, ks2 = 0x1BD11BDBu;  // 0^1^0x1BD11BDA
  uint32_t x0 = (uint32_t)i + ks0;
  uint32_t x1 = (uint32_t)(640 + i) + ks1;
  tf_round(x0,x1,13); tf_round(x0,x1,15); tf_round(x0,x1,26); tf_round(x0,x1,6);
  x0 += ks1; x1 += ks2 + 1u;
  tf_round(x0,x1,17); tf_round(x0,x1,29); tf_round(x0,x1,16); tf_round(x0,x1,24);
  x0 += ks2; x1 += ks0 + 2u;
  tf_round(x0,x1,13); tf_round(x0,x1,15); tf_round(x0,x1,26); tf_round(x0,x1,6);
  x0 += ks0; x1 += ks1 + 3u;
  tf_round(x0,x1,17); tf_round(x0,x1,29); tf_round(x0,x1,16); tf_round(x0,x1,24);
  x0 += ks1; x1 += ks2 + 4u;
  tf_round(x0,x1,13); tf_round(x0,x1,15); tf_round(x0,x1,26); tf_round(x0,x1,6);
  x0 += ks2; x1 += ks0 + 5u;
  u[i]       = bits_to_normal(x0);
  u[640 + i] = bits_to_normal(x1);
}

// ---------------- power iteration: s[b] = u^T A v after 10 iters ----------------
__global__ __launch_bounds__(256) void power_kernel(const float* __restrict__ pm,
                                                    const float* __restrict__ u_in,
                                                    float* __restrict__ s_out) {
  const int b = blockIdx.x, tid = threadIdx.x;
  const float* A = pm + (size_t)b * CC;
  __shared__ float uv[256], vv[256], red[256];
  uv[tid] = u_in[b * 256 + tid];
  __syncthreads();
  for (int it = 0; it < PIT; ++it) {
    float vj = 0.f;
    for (int i = 0; i < 256; ++i) vj = fmaf(A[i * 256 + tid], uv[i], vj);
    red[tid] = vj * vj; __syncthreads();
    for (int off = 128; off > 0; off >>= 1) { if (tid < off) red[tid] += red[tid + off]; __syncthreads(); }
    float nv = sqrtf(red[0]); __syncthreads();
    vv[tid] = vj / nv; __syncthreads();
    float ui = 0.f;
    for (int j = 0; j < 256; ++j) ui = fmaf(A[tid * 256 + j], vv[j], ui);
    red[tid] = ui * ui; __syncthreads();
    for (int off = 128; off > 0; off >>= 1) { if (tid < off) red[tid] += red[tid + off]; __syncthreads(); }
    float nu = sqrtf(red[0]); __syncthreads();
    uv[tid] = ui / nu; __syncthreads();
  }
  float ri = 0.f;
  for (int j = 0; j < 256; ++j) ri = fmaf(A[tid * 256 + j], vv[j], ri);
  red[tid] = ri * uv[tid]; __syncthreads();
  for (int off = 128; off > 0; off >>= 1) { if (tid < off) red[tid] += red[tid + off]; __syncthreads(); }
  if (tid == 0) s_out[b] = red[0];
}

__global__ __launch_bounds__(256) void scale_kernel(const float* __restrict__ pm,
                                                    const float* __restrict__ s,
                                                    float* __restrict__ w) {
  int idx = blockIdx.x * 256 + threadIdx.x;  // grid covers exactly 5*CC
  int b = idx >> 16;
  w[idx] = pm[idx] / s[b];
}

// ---------------- generic 64x64 tile C += A@B (row-major, lda=ldb=256) ----------------
__device__ __forceinline__ void gemm_nn_accum(const float* __restrict__ A,
                                              const float* __restrict__ Bm,
                                              int i0, int k0, int jlen, int tid,
                                              float (*as)[36], float (*bs)[68],
                                              float acc[4][4]) {
  const int ti = tid >> 4, tk = tid & 15;
  for (int j0 = 0; j0 < jlen; j0 += 32) {
    __syncthreads();
    for (int idx = tid; idx < 64 * 32; idx += 256) {
      int jj = idx & 31, ii = idx >> 5;
      as[ii][jj] = A[(i0 + ii) * 256 + j0 + jj];
    }
    for (int idx = tid; idx < 32 * 64; idx += 256) {
      int kk = idx & 63, jj = idx >> 6;
      bs[jj][kk] = Bm[(j0 + jj) * 256 + k0 + kk];
    }
    __syncthreads();
#pragma unroll
    for (int jj = 0; jj < 32; jj += 4) {
      float a4[4][4], b4[4][4];
#pragma unroll
      for (int ii = 0; ii < 4; ++ii) {
        float4 t = *(const float4*)&as[4 * ti + ii][jj];
        a4[ii][0] = t.x; a4[ii][1] = t.y; a4[ii][2] = t.z; a4[ii][3] = t.w;
      }
#pragma unroll
      for (int m = 0; m < 4; ++m) {
        float4 t = *(const float4*)&bs[jj + m][4 * tk];
        b4[m][0] = t.x; b4[m][1] = t.y; b4[m][2] = t.z; b4[m][3] = t.w;
      }
#pragma unroll
      for (int ii = 0; ii < 4; ++ii)
#pragma unroll
        for (int m = 0; m < 4; ++m)
#pragma unroll
          for (int kk = 0; kk < 4; ++kk)
            acc[ii][kk] = fmaf(a4[ii][m], b4[m][kk], acc[ii][kk]);
    }
  }
}

// ---------------- Bjorck: wtw = w^T w ----------------
__global__ __launch_bounds__(256) void gram_kernel(const float* __restrict__ w,
                                                   float* __restrict__ g) {
  const int b = blockIdx.y, tile = blockIdx.x, tid = threadIdx.x;
  const int p0 = (tile >> 2) * 64, q0 = (tile & 3) * 64;
  const int tp = tid >> 4, tq = tid & 15;
  const float* A = w + (size_t)b * CC;
  __shared__ float as[32][68], bs[32][68];
  float acc[4][4] = {};
  for (int r0 = 0; r0 < 256; r0 += 32) {
    __syncthreads();
    for (int idx = tid; idx < 32 * 64; idx += 256) {
      int c = idx & 63, r = idx >> 6;
      as[r][c] = A[(r0 + r) * 256 + p0 + c];
      bs[r][c] = A[(r0 + r) * 256 + q0 + c];
    }
    __syncthreads();
#pragma unroll
    for (int r = 0; r < 32; ++r) {
      float4 a4 = *(const float4*)&as[r][4 * tp];
      float4 b4 = *(const float4*)&bs[r][4 * tq];
      float av[4] = {a4.x, a4.y, a4.z, a4.w}, bv[4] = {b4.x, b4.y, b4.z, b4.w};
#pragma unroll
      for (int pi = 0; pi < 4; ++pi)
#pragma unroll
        for (int qi = 0; qi < 4; ++qi)
          acc[pi][qi] = fmaf(av[pi], bv[qi], acc[pi][qi]);
    }
  }
  for (int pi = 0; pi < 4; ++pi) {
    float4 o = {acc[pi][0], acc[pi][1], acc[pi][2], acc[pi][3]};
    *(float4*)&g[(size_t)b * CC + (p0 + 4 * tp + pi) * 256 + q0 + 4 * tq] = o;
  }
}

// ---------------- Bjorck: w_out = 1.5 w - 0.5 w@wtw ----------------
__global__ __launch_bounds__(256) void update_kernel(const float* __restrict__ w_in,
                                                     const float* __restrict__ g,
                                                     float* __restrict__ w_out) {
  const int b = blockIdx.y, tile = blockIdx.x, tid = threadIdx.x;
  const int i0 = (tile >> 2) * 64, k0 = (tile & 3) * 64;
  const int ti = tid >> 4, tk = tid & 15;
  __shared__ float as[64][36];
  __shared__ float bs[32][68];
  float acc[4][4] = {};
  gemm_nn_accum(w_in + (size_t)b * CC, g + (size_t)b * CC, i0, k0, 256, tid, as, bs, acc);
  for (int ii = 0; ii < 4; ++ii) {
    size_t off = (size_t)b * CC + (i0 + 4 * ti + ii) * 256 + k0 + 4 * tk;
    float4 wv = *(const float4*)&w_in[off];
    float4 o;
    o.x = 1.5f * wv.x - 0.5f * acc[ii][0];
    o.y = 1.5f * wv.y - 0.5f * acc[ii][1];
    o.z = 1.5f * wv.z - 0.5f * acc[ii][2];
    o.w = 1.5f * wv.w - 0.5f * acc[ii][3];
    *(float4*)&w_out[off] = o;
  }
}

// ---------------- PQ[b] = V V^T, V = ortho[1+b][:, :128] ----------------
__global__ __launch_bounds__(256) void pq_kernel(const float* __restrict__ w,
                                                 float* __restrict__ PQ) {
  const int b = blockIdx.y, tile = blockIdx.x, tid = threadIdx.x;
  const int i0 = (tile >> 2) * 64, k0 = (tile & 3) * 64;
  const int ti = tid >> 4, tk = tid & 15;
  const float* V = w + (size_t)(1 + b) * CC;
  __shared__ float as[64][36], bs[64][36];
  float acc[4][4] = {};
  for (int j0 = 0; j0 < 128; j0 += 32) {
    __syncthreads();
    for (int idx = tid; idx < 64 * 32; idx += 256) {
      int jj = idx & 31, ii = idx >> 5;
      as[ii][jj] = V[(i0 + ii) * 256 + j0 + jj];
      bs[ii][jj] = V[(k0 + ii) * 256 + j0 + jj];
    }
    __syncthreads();
#pragma unroll
    for (int jj = 0; jj < 32; jj += 4) {
      float a4[4][4], b4[4][4];
#pragma unroll
      for (int ii = 0; ii < 4; ++ii) {
        float4 t = *(const float4*)&as[4 * ti + ii][jj];
        a4[ii][0] = t.x; a4[ii][1] = t.y; a4[ii][2] = t.z; a4[ii][3] = t.w;
      }
#pragma unroll
      for (int kk = 0; kk < 4; ++kk) {
        float4 t = *(const float4*)&bs[4 * tk + kk][jj];
        b4[kk][0] = t.x; b4[kk][1] = t.y; b4[kk][2] = t.z; b4[kk][3] = t.w;
      }
#pragma unroll
      for (int ii = 0; ii < 4; ++ii)
#pragma unroll
        for (int kk = 0; kk < 4; ++kk)
#pragma unroll
          for (int d = 0; d < 4; ++d)
            acc[ii][kk] = fmaf(a4[ii][d], b4[kk][d], acc[ii][kk]);
    }
  }
  for (int ii = 0; ii < 4; ++ii) {
    float4 o = {acc[ii][0], acc[ii][1], acc[ii][2], acc[ii][3]};
    *(float4*)&PQ[(size_t)b * CC + (i0 + 4 * ti + ii) * 256 + k0 + 4 * tk] = o;
  }
}

// ---------------- C01[g] = PQ[2g] @ PQ[2g+1] ----------------
__global__ __launch_bounds__(256) void bo_mm_kernel(const float* __restrict__ PQ,
                                                    float* __restrict__ C01) {
  const int gидx = blockIdx.y, tile = blockIdx.x, tid = threadIdx.x;
  const int i0 = (tile >> 2) * 64, k0 = (tile & 3) * 64;
  const int ti = tid >> 4, tk = tid & 15;
  __shared__ float as[64][36];
  __shared__ float bs[32][68];
  float acc[4][4] = {};
  gemm_nn_accum(PQ + (size_t)(2 * gидx) * CC, PQ + (size_t)(2 * gидx + 1) * CC,
                i0, k0, 256, tid, as, bs, acc);
  for (int ii = 0; ii < 4; ++ii) {
    float4 o = {acc[ii][0], acc[ii][1], acc[ii][2], acc[ii][3]};
    *(float4*)&C01[(size_t)gидx * CC + (i0 + 4 * ti + ii) * 256 + k0 + 4 * tk] = o;
  }
}

// ---------------- build m1[2][2], m2[2][2] elementwise ----------------
__global__ __launch_bounds__(256) void bo_elem_kernel(const float* __restrict__ PQ,
                                                      const float* __restrict__ C01,
                                                      float* __restrict__ m) {
  int idx = blockIdx.x * 256 + threadIdx.x;  // covers CC
  int i = idx >> 8, j = idx & 255;
  float e = (i == j) ? 1.f : 0.f;
  float p1 = PQ[idx], p2 = PQ[CC + idx], c = C01[idx];
  m[idx]          = c;                    // p1 p2
  m[CC + idx]     = p1 - c;               // p1 q2
  m[2 * CC + idx] = p2 - c;               // q1 p2
  m[3 * CC + idx] = e - p1 - p2 + c;      // q1 q2
  float p3 = PQ[2 * CC + idx], p4 = PQ[3 * CC + idx], c2 = C01[CC + idx];
  m[4 * CC + idx] = c2;
  m[5 * CC + idx] = p3 - c2;
  m[6 * CC + idx] = p4 - c2;
  m[7 * CC + idx] = e - p3 - p4 + c2;
}

// ---------------- p3[k][l] = sum m1[i1][j1] @ m2[k-i1][l-j1] ----------------
__global__ __launch_bounds__(256) void mconv_kernel(const float* __restrict__ m,
                                                    float* __restrict__ p3) {
  const int v = blockIdx.y;                 // k*3 + l
  const int k = v / 3, l = v % 3;
  const int tile = blockIdx.x, tid = threadIdx.x;
  const int i0 = (tile >> 2) * 64, k0 = (tile & 3) * 64;
  const int ti = tid >> 4, tk = tid & 15;
  __shared__ float as[64][36];
  __shared__ float bs[32][68];
  float acc[4][4] = {};
  for (int i1 = 0; i1 < 2; ++i1) {
    int i2 = k - i1; if (i2 < 0 || i2 > 1) continue;
    for (int j1 = 0; j1 < 2; ++j1) {
      int j2 = l - j1; if (j2 < 0 || j2 > 1) continue;
      gemm_nn_accum(m + (size_t)(i1 * 2 + j1) * CC, m + (size_t)(4 + i2 * 2 + j2) * CC,
                    i0, k0, 256, tid, as, bs, acc);
    }
  }
  for (int ii = 0; ii < 4; ++ii) {
    float4 o = {acc[ii][0], acc[ii][1], acc[ii][2], acc[ii][3]};
    *(float4*)&p3[(size_t)v * CC + (i0 + 4 * ti + ii) * 256 + k0 + 4 * tk] = o;
  }
}

// ---------------- Wc[i][tap=kh*3+kw][o] = sum_c H[i][c] p3[kw][kh][c][o] ----------------
__global__ __launch_bounds__(256) void wT_kernel(const float* __restrict__ ortho,
                                                 const float* __restrict__ p3,
                                                 float* __restrict__ wc) {
  const int v = blockIdx.y;                 // p3 slot: k*3 + l
  const int k = v / 3, l = v % 3;
  const int tapw = l * 3 + k;               // weight tap index kh*3+kw with kh=l, kw=k
  const int tile = blockIdx.x, tid = threadIdx.x;
  const int i0 = (tile >> 2) * 64, o0 = (tile & 3) * 64;
  const int ti = tid >> 4, tk = tid & 15;
  __shared__ float as[64][36];
  __shared__ float bs[32][68];
  float acc[4][4] = {};
  gemm_nn_accum(ortho /*H = ortho[0]*/, p3 + (size_t)v * CC, i0, o0, 256, tid, as, bs, acc);
  for (int ii = 0; ii < 4; ++ii) {
    float4 o = {acc[ii][0], acc[ii][1], acc[ii][2], acc[ii][3]};
    *(float4*)&wc[(size_t)(i0 + 4 * ti + ii) * 2304 + tapw * 256 + o0 + 4 * tk] = o;
  }
}

// ---------------- circular 3x3 conv + bias, fp32 direct ----------------
// grid (og=2, yp=32, b=16), block 256. Tile: 128 o x 2 rows x 64 cols.
__global__ __launch_bounds__(256) void conv_kernel(const float* __restrict__ x,
                                                   const float* __restrict__ wc,
                                                   const float* __restrict__ bias,
                                                   float* __restrict__ out) {
  __shared__ float xs[4 * 8 * 68];     // [row 0..3][ic 0..7][col 0..65 (pad 68)]
  __shared__ float wl[8 * 9 * 128];    // [(i*9+tap)*128 + o_local]
  const int og = blockIdx.x, yp = blockIdx.y, b = blockIdx.z;
  const int tid = threadIdx.x;
  const int tx = tid & 15, to = tid >> 4;
  const int y2 = yp * 2;
  float acc[8][2][4];
#pragma unroll
  for (int oi = 0; oi < 8; ++oi)
#pragma unroll
    for (int oy = 0; oy < 2; ++oy)
#pragma unroll
      for (int xi = 0; xi < 4; ++xi) acc[oi][oy][xi] = 0.f;

  for (int ic0 = 0; ic0 < 256; ic0 += 8) {
    __syncthreads();
    for (int idx = tid; idx < 4 * 8 * 66; idx += 256) {
      int cpos = idx % 66, rem = idx / 66;
      int i = rem & 7, row = rem >> 3;
      int rowabs = (y2 - 1 + row + 64) & 63;
      int colabs = (cpos + 63) & 63;
      xs[(row * 8 + i) * 68 + cpos] =
          x[(((size_t)b * 256 + ic0 + i) * 64 + rowabs) * 64 + colabs];
    }
    for (int idx = tid; idx < 8 * 9 * 128; idx += 256) {
      int o = idx & 127, it = idx >> 7;
      int i = it / 9, tap = it % 9;
      wl[idx] = wc[(size_t)(ic0 + i) * 2304 + tap * 256 + og * 128 + o];
    }
    __syncthreads();
    for (int i = 0; i < 8; ++i) {
      float xv[4][6];
#pragma unroll
      for (int row = 0; row < 4; ++row) {
        const float* xr = &xs[(row * 8 + i) * 68 + 4 * tx];
        float4 a = *(const float4*)xr;
        float2 b2 = *(const float2*)(xr + 4);
        xv[row][0] = a.x; xv[row][1] = a.y; xv[row][2] = a.z; xv[row][3] = a.w;
        xv[row][4] = b2.x; xv[row][5] = b2.y;
      }
#pragma unroll
      for (int tap = 0; tap < 9; ++tap) {
        const int r = tap / 3, t = tap % 3;
        const float* wr = &wl[(i * 9 + tap) * 128 + to * 8];
        float4 w0 = *(const float4*)wr;
        float4 w1 = *(const float4*)(wr + 4);
        float wv[8] = {w0.x, w0.y, w0.z, w0.w, w1.x, w1.y, w1.z, w1.w};
#pragma unroll
        for (int oi = 0; oi < 8; ++oi)
#pragma unroll
          for (int oy = 0; oy < 2; ++oy)
#pragma unroll
            for (int xi = 0; xi < 4; ++xi)
              acc[oi][oy][xi] = fmaf(wv[oi], xv[oy + r][xi + t], acc[oi][oy][xi]);
      }
    }
  }
  for (int oi = 0; oi < 8; ++oi) {
    const int o = og * 128 + to * 8 + oi;
    const float bv = bias[o];
    for (int oy = 0; oy < 2; ++oy) {
      float4 v = {acc[oi][oy][0] + bv, acc[oi][oy][1] + bv,
                  acc[oi][oy][2] + bv, acc[oi][oy][3] + bv};
      *(float4*)&out[(((size_t)b * 256 + o) * 64 + y2 + oy) * 64 + tx * 4] = v;
    }
  }
}

extern "C" void kernel_launch(void* const* d_in, const int* in_sizes, int n_in,
                              void* d_out, int out_size, void* d_ws, size_t ws_size,
                              hipStream_t stream) {
  const float* x    = (const float*)d_in[0];
  const float* pm   = (const float*)d_in[1];
  const float* bias = (const float*)d_in[2];
  float* out = (float*)d_out;
  float* ws  = (float*)d_ws;

  float* u   = ws + OFF_U;
  float* s   = ws + OFF_S;
  float* wA  = ws + OFF_WA;
  float* wB  = ws + OFF_WB;
  float* g   = ws + OFF_G;
  float* PQ  = ws + OFF_PQ;
  float* C01 = ws + OFF_C01;
  float* m   = ws + OFF_M;
  float* p3  = ws + OFF_P3;
  float* wc  = ws + OFF_WC;

  gen_u_kernel<<<3, 256, 0, stream>>>(u);
  power_kernel<<<5, 256, 0, stream>>>(pm, u, s);
  scale_kernel<<<1280, 256, 0, stream>>>(pm, s, wA);

  float* cur = wA;
  float* nxt = wB;
  for (int it = 0; it < BJORCK; ++it) {
    gram_kernel<<<dim3(16, 5), 256, 0, stream>>>(cur, g);
    update_kernel<<<dim3(16, 5), 256, 0, stream>>>(cur, g, nxt);
    float* tmp = cur; cur = nxt; nxt = tmp;
  }

  pq_kernel<<<dim3(16, 4), 256, 0, stream>>>(cur, PQ);
  bo_mm_kernel<<<dim3(16, 2), 256, 0, stream>>>(PQ, C01);
  bo_elem_kernel<<<256, 256, 0, stream>>>(PQ, C01, m);
  mconv_kernel<<<dim3(16, 9), 256, 0, stream>>>(m, p3);
  wT_kernel<<<dim3(16, 9), 256, 0, stream>>>(cur, p3, wc);

  conv_kernel<<<dim3(2, 32, 16), 256, 0, stream>>>(x, wc, bias, out);
}

// Round 2
// 1099.376 us; speedup vs baseline: 2.2505x; 2.2505x over previous
//
#include <hip/hip_runtime.h>
#include <stdint.h>

typedef _Float16 f16;
typedef _Float16 f16x8 __attribute__((ext_vector_type(8)));
typedef float f32x4 __attribute__((ext_vector_type(4)));

namespace {
constexpr int C  = 256;
constexpr int CC = C * C;            // 65536
constexpr int BJORCK = 20;
constexpr int PIT = 10;

// workspace layout in floats
constexpr size_t OFF_U   = 0;                  // 1280
constexpr size_t OFF_S   = 1280;               // 5 (padded)
constexpr size_t OFF_WA  = 2048;               // 5*CC
constexpr size_t OFF_WB  = OFF_WA  + 5 * CC;
constexpr size_t OFF_G   = OFF_WB  + 5 * CC;   // wtw, 5*CC; later aliased by wcb (f16, 1.18MB < 1.31MB)
constexpr size_t OFF_PQ  = OFF_G   + 5 * CC;   // 4*CC
constexpr size_t OFF_C01 = OFF_PQ  + 4 * CC;   // 2*CC
constexpr size_t OFF_M   = OFF_C01 + 2 * CC;   // 8*CC
constexpr size_t OFF_P3  = OFF_M   + 8 * CC;   // 9*CC
}

// ---------------- threefry2x32 + XLA erfinv (bit-matched to JAX) ----------------
__device__ __forceinline__ void tf_round(uint32_t& x0, uint32_t& x1, int r) {
  x0 += x1; x1 = (x1 << r) | (x1 >> (32 - r)); x1 ^= x0;
}

__device__ __forceinline__ float erfinv_f32(float x) {
  float w = -log1pf(-x * x);
  float p;
  if (w < 5.0f) {
    w -= 2.5f;
    p = 2.81022636e-08f;
    p = fmaf(p, w, 3.43273939e-07f);
    p = fmaf(p, w, -3.5233877e-06f);
    p = fmaf(p, w, -4.39150654e-06f);
    p = fmaf(p, w, 0.00021858087f);
    p = fmaf(p, w, -0.00125372503f);
    p = fmaf(p, w, -0.00417768164f);
    p = fmaf(p, w, 0.246640727f);
    p = fmaf(p, w, 1.50140941f);
  } else {
    w = sqrtf(w) - 3.0f;
    p = -0.000200214257f;
    p = fmaf(p, w, 0.000100950558f);
    p = fmaf(p, w, 0.00134934322f);
    p = fmaf(p, w, -0.00367342844f);
    p = fmaf(p, w, 0.00573950773f);
    p = fmaf(p, w, -0.0076224613f);
    p = fmaf(p, w, 0.00943887047f);
    p = fmaf(p, w, 1.00167406f);
    p = fmaf(p, w, 2.83297682f);
  }
  return p * x;
}

__device__ __forceinline__ float bits_to_normal(uint32_t bits) {
  float f = __uint_as_float((bits >> 9) | 0x3F800000u) - 1.0f;
  const float lo = -0.99999994f;
  float uu = fmaxf(lo, f * 2.0f + lo);
  return 1.41421356f * erfinv_f32(uu);
}

__global__ __launch_bounds__(256) void gen_u_kernel(float* __restrict__ u) {
  int i = blockIdx.x * 256 + threadIdx.x;
  if (i >= 640) return;
  const uint32_t ks0 = 0u, ks1 = 1u, ks2 = 0x1BD11BDBu;
  uint32_t x0 = (uint32_t)i + ks0;
  uint32_t x1 = (uint32_t)(640 + i) + ks1;
  tf_round(x0,x1,13); tf_round(x0,x1,15); tf_round(x0,x1,26); tf_round(x0,x1,6);
  x0 += ks1; x1 += ks2 + 1u;
  tf_round(x0,x1,17); tf_round(x0,x1,29); tf_round(x0,x1,16); tf_round(x0,x1,24);
  x0 += ks2; x1 += ks0 + 2u;
  tf_round(x0,x1,13); tf_round(x0,x1,15); tf_round(x0,x1,26); tf_round(x0,x1,6);
  x0 += ks0; x1 += ks1 + 3u;
  tf_round(x0,x1,17); tf_round(x0,x1,29); tf_round(x0,x1,16); tf_round(x0,x1,24);
  x0 += ks1; x1 += ks2 + 4u;
  tf_round(x0,x1,13); tf_round(x0,x1,15); tf_round(x0,x1,26); tf_round(x0,x1,6);
  x0 += ks2; x1 += ks0 + 5u;
  u[i]       = bits_to_normal(x0);
  u[640 + i] = bits_to_normal(x1);
}

// ---------------- power iteration ----------------
__global__ __launch_bounds__(256) void power_kernel(const float* __restrict__ pm,
                                                    const float* __restrict__ u_in,
                                                    float* __restrict__ s_out) {
  const int b = blockIdx.x, tid = threadIdx.x;
  const float* A = pm + (size_t)b * CC;
  __shared__ float uv[256], vv[256], red[256];
  uv[tid] = u_in[b * 256 + tid];
  __syncthreads();
  for (int it = 0; it < PIT; ++it) {
    float vj = 0.f;
    for (int i = 0; i < 256; ++i) vj = fmaf(A[i * 256 + tid], uv[i], vj);
    red[tid] = vj * vj; __syncthreads();
    for (int off = 128; off > 0; off >>= 1) { if (tid < off) red[tid] += red[tid + off]; __syncthreads(); }
    float nv = sqrtf(red[0]); __syncthreads();
    vv[tid] = vj / nv; __syncthreads();
    float ui = 0.f;
    for (int j = 0; j < 256; ++j) ui = fmaf(A[tid * 256 + j], vv[j], ui);
    red[tid] = ui * ui; __syncthreads();
    for (int off = 128; off > 0; off >>= 1) { if (tid < off) red[tid] += red[tid + off]; __syncthreads(); }
    float nu = sqrtf(red[0]); __syncthreads();
    uv[tid] = ui / nu; __syncthreads();
  }
  float ri = 0.f;
  for (int j = 0; j < 256; ++j) ri = fmaf(A[tid * 256 + j], vv[j], ri);
  red[tid] = ri * uv[tid]; __syncthreads();
  for (int off = 128; off > 0; off >>= 1) { if (tid < off) red[tid] += red[tid + off]; __syncthreads(); }
  if (tid == 0) s_out[b] = red[0];
}

__global__ __launch_bounds__(256) void scale_kernel(const float* __restrict__ pm,
                                                    const float* __restrict__ s,
                                                    float* __restrict__ w) {
  int idx = blockIdx.x * 256 + threadIdx.x;
  int b = idx >> 16;
  w[idx] = pm[idx] / s[b];
}

// ---------------- Bjorck 32x32-tile kernels (320 wg) ----------------
__global__ __launch_bounds__(256) void gram32_kernel(const float* __restrict__ w,
                                                     float* __restrict__ g) {
  const int b = blockIdx.y, t = blockIdx.x, tid = threadIdx.x;
  const int p0 = (t >> 3) * 32, q0 = (t & 7) * 32;
  const int tp = tid >> 4, tq = tid & 15;
  const float* A = w + (size_t)b * CC;
  __shared__ float as[32][34], bs[32][34];
  float acc[2][2] = {};
  for (int r0 = 0; r0 < 256; r0 += 32) {
    __syncthreads();
    for (int idx = tid; idx < 1024; idx += 256) {
      int r = idx >> 5, cc = idx & 31;
      as[r][cc] = A[(r0 + r) * 256 + p0 + cc];
      bs[r][cc] = A[(r0 + r) * 256 + q0 + cc];
    }
    __syncthreads();
#pragma unroll
    for (int r = 0; r < 32; ++r) {
      float2 av = *(const float2*)&as[r][2 * tp];
      float2 bv = *(const float2*)&bs[r][2 * tq];
      acc[0][0] = fmaf(av.x, bv.x, acc[0][0]);
      acc[0][1] = fmaf(av.x, bv.y, acc[0][1]);
      acc[1][0] = fmaf(av.y, bv.x, acc[1][0]);
      acc[1][1] = fmaf(av.y, bv.y, acc[1][1]);
    }
  }
#pragma unroll
  for (int pi = 0; pi < 2; ++pi) {
    float2 o = {acc[pi][0], acc[pi][1]};
    *(float2*)&g[(size_t)b * CC + (p0 + 2 * tp + pi) * 256 + q0 + 2 * tq] = o;
  }
}

__global__ __launch_bounds__(256) void update32_kernel(const float* __restrict__ w_in,
                                                       const float* __restrict__ g,
                                                       float* __restrict__ w_out) {
  const int b = blockIdx.y, t = blockIdx.x, tid = threadIdx.x;
  const int i0 = (t >> 3) * 32, k0 = (t & 7) * 32;
  const int tp = tid >> 4, tq = tid & 15;
  const float* A = w_in + (size_t)b * CC;
  const float* Bm = g + (size_t)b * CC;
  __shared__ float as[32][34], bs[32][34];
  float acc[2][2] = {};
  for (int j0 = 0; j0 < 256; j0 += 32) {
    __syncthreads();
    for (int idx = tid; idx < 1024; idx += 256) {
      int r = idx >> 5, cc = idx & 31;
      as[r][cc] = A[(i0 + r) * 256 + j0 + cc];   // A rows block, transposed use
      bs[r][cc] = Bm[(j0 + r) * 256 + k0 + cc];
    }
    __syncthreads();
#pragma unroll
    for (int r = 0; r < 32; ++r) {
      // as holds A[i0+rr][j0+cc] with rr index = first idx: need A[i][j]: a = as[i_local][r]
      float2 av = {as[2 * tp][r], as[2 * tp + 1][r]};
      float2 bv = *(const float2*)&bs[r][2 * tq];
      acc[0][0] = fmaf(av.x, bv.x, acc[0][0]);
      acc[0][1] = fmaf(av.x, bv.y, acc[0][1]);
      acc[1][0] = fmaf(av.y, bv.x, acc[1][0]);
      acc[1][1] = fmaf(av.y, bv.y, acc[1][1]);
    }
  }
#pragma unroll
  for (int pi = 0; pi < 2; ++pi) {
    size_t off = (size_t)b * CC + (i0 + 2 * tp + pi) * 256 + k0 + 2 * tq;
    float2 wv = *(const float2*)&w_in[off];
    float2 o = {1.5f * wv.x - 0.5f * acc[pi][0], 1.5f * wv.y - 0.5f * acc[pi][1]};
    *(float2*)&w_out[off] = o;
  }
}

// ---------------- generic 64x64 tile C += A@B (row-major, lda=ldb=256) ----------------
__device__ __forceinline__ void gemm_nn_accum(const float* __restrict__ A,
                                              const float* __restrict__ Bm,
                                              int i0, int k0, int jlen, int tid,
                                              float (*as)[36], float (*bs)[68],
                                              float acc[4][4]) {
  const int ti = tid >> 4, tk = tid & 15;
  for (int j0 = 0; j0 < jlen; j0 += 32) {
    __syncthreads();
    for (int idx = tid; idx < 64 * 32; idx += 256) {
      int jj = idx & 31, ii = idx >> 5;
      as[ii][jj] = A[(i0 + ii) * 256 + j0 + jj];
    }
    for (int idx = tid; idx < 32 * 64; idx += 256) {
      int kk = idx & 63, jj = idx >> 6;
      bs[jj][kk] = Bm[(j0 + jj) * 256 + k0 + kk];
    }
    __syncthreads();
#pragma unroll
    for (int jj = 0; jj < 32; jj += 4) {
      float a4[4][4], b4[4][4];
#pragma unroll
      for (int ii = 0; ii < 4; ++ii) {
        float4 t = *(const float4*)&as[4 * ti + ii][jj];
        a4[ii][0] = t.x; a4[ii][1] = t.y; a4[ii][2] = t.z; a4[ii][3] = t.w;
      }
#pragma unroll
      for (int m = 0; m < 4; ++m) {
        float4 t = *(const float4*)&bs[jj + m][4 * tk];
        b4[m][0] = t.x; b4[m][1] = t.y; b4[m][2] = t.z; b4[m][3] = t.w;
      }
#pragma unroll
      for (int ii = 0; ii < 4; ++ii)
#pragma unroll
        for (int m = 0; m < 4; ++m)
#pragma unroll
          for (int kk = 0; kk < 4; ++kk)
            acc[ii][kk] = fmaf(a4[ii][m], b4[m][kk], acc[ii][kk]);
    }
  }
}

// ---------------- PQ[b] = V V^T, V = ortho[1+b][:, :128] ----------------
__global__ __launch_bounds__(256) void pq_kernel(const float* __restrict__ w,
                                                 float* __restrict__ PQ) {
  const int b = blockIdx.y, tile = blockIdx.x, tid = threadIdx.x;
  const int i0 = (tile >> 2) * 64, k0 = (tile & 3) * 64;
  const int ti = tid >> 4, tk = tid & 15;
  const float* V = w + (size_t)(1 + b) * CC;
  __shared__ float as[64][36], bs[64][36];
  float acc[4][4] = {};
  for (int j0 = 0; j0 < 128; j0 += 32) {
    __syncthreads();
    for (int idx = tid; idx < 64 * 32; idx += 256) {
      int jj = idx & 31, ii = idx >> 5;
      as[ii][jj] = V[(i0 + ii) * 256 + j0 + jj];
      bs[ii][jj] = V[(k0 + ii) * 256 + j0 + jj];
    }
    __syncthreads();
#pragma unroll
    for (int jj = 0; jj < 32; jj += 4) {
      float a4[4][4], b4[4][4];
#pragma unroll
      for (int ii = 0; ii < 4; ++ii) {
        float4 t = *(const float4*)&as[4 * ti + ii][jj];
        a4[ii][0] = t.x; a4[ii][1] = t.y; a4[ii][2] = t.z; a4[ii][3] = t.w;
      }
#pragma unroll
      for (int kk = 0; kk < 4; ++kk) {
        float4 t = *(const float4*)&bs[4 * tk + kk][jj];
        b4[kk][0] = t.x; b4[kk][1] = t.y; b4[kk][2] = t.z; b4[kk][3] = t.w;
      }
#pragma unroll
      for (int ii = 0; ii < 4; ++ii)
#pragma unroll
        for (int kk = 0; kk < 4; ++kk)
#pragma unroll
          for (int d = 0; d < 4; ++d)
            acc[ii][kk] = fmaf(a4[ii][d], b4[kk][d], acc[ii][kk]);
    }
  }
  for (int ii = 0; ii < 4; ++ii) {
    float4 o = {acc[ii][0], acc[ii][1], acc[ii][2], acc[ii][3]};
    *(float4*)&PQ[(size_t)b * CC + (i0 + 4 * ti + ii) * 256 + k0 + 4 * tk] = o;
  }
}

// ---------------- C01[g] = PQ[2g] @ PQ[2g+1] ----------------
__global__ __launch_bounds__(256) void bo_mm_kernel(const float* __restrict__ PQ,
                                                    float* __restrict__ C01) {
  const int gx = blockIdx.y, tile = blockIdx.x, tid = threadIdx.x;
  const int i0 = (tile >> 2) * 64, k0 = (tile & 3) * 64;
  const int ti = tid >> 4, tk = tid & 15;
  __shared__ float as[64][36];
  __shared__ float bs[32][68];
  float acc[4][4] = {};
  gemm_nn_accum(PQ + (size_t)(2 * gx) * CC, PQ + (size_t)(2 * gx + 1) * CC,
                i0, k0, 256, tid, as, bs, acc);
  for (int ii = 0; ii < 4; ++ii) {
    float4 o = {acc[ii][0], acc[ii][1], acc[ii][2], acc[ii][3]};
    *(float4*)&C01[(size_t)gx * CC + (i0 + 4 * ti + ii) * 256 + k0 + 4 * tk] = o;
  }
}

// ---------------- build m1[2][2], m2[2][2] elementwise ----------------
__global__ __launch_bounds__(256) void bo_elem_kernel(const float* __restrict__ PQ,
                                                      const float* __restrict__ C01,
                                                      float* __restrict__ m) {
  int idx = blockIdx.x * 256 + threadIdx.x;
  int i = idx >> 8, j = idx & 255;
  float e = (i == j) ? 1.f : 0.f;
  float p1 = PQ[idx], p2 = PQ[CC + idx], c = C01[idx];
  m[idx]          = c;
  m[CC + idx]     = p1 - c;
  m[2 * CC + idx] = p2 - c;
  m[3 * CC + idx] = e - p1 - p2 + c;
  float p3 = PQ[2 * CC + idx], p4 = PQ[3 * CC + idx], c2 = C01[CC + idx];
  m[4 * CC + idx] = c2;
  m[5 * CC + idx] = p3 - c2;
  m[6 * CC + idx] = p4 - c2;
  m[7 * CC + idx] = e - p3 - p4 + c2;
}

// ---------------- p3[k][l] = sum m1[i1][j1] @ m2[k-i1][l-j1] ----------------
__global__ __launch_bounds__(256) void mconv_kernel(const float* __restrict__ m,
                                                    float* __restrict__ p3) {
  const int v = blockIdx.y;
  const int k = v / 3, l = v % 3;
  const int tile = blockIdx.x, tid = threadIdx.x;
  const int i0 = (tile >> 2) * 64, k0 = (tile & 3) * 64;
  const int ti = tid >> 4, tk = tid & 15;
  __shared__ float as[64][36];
  __shared__ float bs[32][68];
  float acc[4][4] = {};
  for (int i1 = 0; i1 < 2; ++i1) {
    int i2 = k - i1; if (i2 < 0 || i2 > 1) continue;
    for (int j1 = 0; j1 < 2; ++j1) {
      int j2 = l - j1; if (j2 < 0 || j2 > 1) continue;
      gemm_nn_accum(m + (size_t)(i1 * 2 + j1) * CC, m + (size_t)(4 + i2 * 2 + j2) * CC,
                    i0, k0, 256, tid, as, bs, acc);
    }
  }
  for (int ii = 0; ii < 4; ++ii) {
    float4 o = {acc[ii][0], acc[ii][1], acc[ii][2], acc[ii][3]};
    *(float4*)&p3[(size_t)v * CC + (i0 + 4 * ti + ii) * 256 + k0 + 4 * tk] = o;
  }
}

// ---------------- wcb[icg][tapw][o][e] f16 = Hmat @ p3 ----------------
__global__ __launch_bounds__(256) void wT_kernel(const float* __restrict__ ortho,
                                                 const float* __restrict__ p3,
                                                 f16* __restrict__ wcb) {
  const int v = blockIdx.y;
  const int k = v / 3, l = v % 3;
  const int tapw = l * 3 + k;               // kh=l, kw=k
  const int tile = blockIdx.x, tid = threadIdx.x;
  const int i0 = (tile >> 2) * 64, o0 = (tile & 3) * 64;
  const int ti = tid >> 4, tk = tid & 15;
  __shared__ float as[64][36];
  __shared__ float bs[32][68];
  float acc[4][4] = {};
  gemm_nn_accum(ortho, p3 + (size_t)v * CC, i0, o0, 256, tid, as, bs, acc);
  for (int ii = 0; ii < 4; ++ii) {
    int ic = i0 + 4 * ti + ii;
    int icg = ic >> 3, e = ic & 7;
    for (int q = 0; q < 4; ++q) {
      int o = o0 + 4 * tk + q;
      wcb[(((size_t)icg * 9 + tapw) * 256 + o) * 8 + e] = (f16)acc[ii][q];
    }
  }
}

// ---------------- circular 3x3 conv via MFMA f16 ----------------
// grid (og=2, yt=16, b=16), block 256 (4 waves). Block tile: 128 o x 4 rows x 64 cols.
__global__ __launch_bounds__(256, 2) void conv_mfma_kernel(const float* __restrict__ x,
                                                           const f16* __restrict__ wcb,
                                                           const float* __restrict__ bias,
                                                           float* __restrict__ out) {
  __shared__ uint4 xs_sh[6 * 4 * 66];   // [row 0..5][g 0..3][col 0..65], 16B units of 8 f16 (ic)
  __shared__ uint4 ws_sh[2][512];       // [buf][g*128 + o], 8 f16 (ic)
  const uint4* wcb4 = (const uint4*)wcb;
  const int og = blockIdx.x, yt = blockIdx.y, b = blockIdx.z;
  const int y0 = yt * 4, o0g = og * 128;
  const int tid = threadIdx.x;
  const int w = tid >> 6, l = tid & 63, g = l >> 4, ln = l & 15;

  f32x4 acc[8][4];
#pragma unroll
  for (int of = 0; of < 8; ++of)
#pragma unroll
    for (int nf = 0; nf < 4; ++nf) { acc[of][nf][0]=0.f; acc[of][nf][1]=0.f; acc[of][nf][2]=0.f; acc[of][nf][3]=0.f; }

  // prologue: stage ws for step 0 (c=0, tap=0) into buf 0
  {
    int u0 = tid, u1 = tid + 256;
    ws_sh[0][u0] = wcb4[(size_t)((u0 >> 7) * 9 + 0) * 256 + o0g + (u0 & 127)];
    ws_sh[0][u1] = wcb4[(size_t)((u1 >> 7) * 9 + 0) * 256 + o0g + (u1 & 127)];
  }

  for (int c = 0; c < 8; ++c) {
    __syncthreads();
    // stage x chunk c: ic = c*32 + gg*8 + e
    for (int u = tid; u < 1584; u += 256) {
      int rg = u / 66, col = u - rg * 66;
      int row = rg >> 2, gg = rg & 3;
      int rowabs = (y0 + row + 63) & 63;
      int colabs = (col + 63) & 63;
      const float* xp = x + (((size_t)b * 256 + c * 32 + gg * 8) * 64 + rowabs) * 64 + colabs;
      union { f16 h[8]; uint4 q; } pk;
#pragma unroll
      for (int e = 0; e < 8; ++e) pk.h[e] = (f16)xp[(size_t)e * 4096];
      xs_sh[u] = pk.q;
    }
    __syncthreads();
#pragma unroll
    for (int tap = 0; tap < 9; ++tap) {
      const int kh = tap / 3, kw = tap % 3;
      const int s = c * 9 + tap;
      const int par = s & 1;
      const bool hasNext = (s + 1 < 72);
      uint4 t0, t1;
      if (hasNext) {
        const int nc = (tap == 8) ? c + 1 : c, ntap = (tap == 8) ? 0 : tap + 1;
        int u0 = tid, u1 = tid + 256;
        t0 = wcb4[(size_t)((nc * 4 + (u0 >> 7)) * 9 + ntap) * 256 + o0g + (u0 & 127)];
        t1 = wcb4[(size_t)((nc * 4 + (u1 >> 7)) * 9 + ntap) * 256 + o0g + (u1 & 127)];
      }
      // fragments
      f16x8 a[8], bf[4];
      const uint4* wb = ws_sh[par];
#pragma unroll
      for (int of = 0; of < 8; ++of)
        a[of] = *(const f16x8*)&wb[g * 128 + of * 16 + ln];
      const int xbase = ((w + kh) * 4 + g) * 66 + ln + kw;
#pragma unroll
      for (int nf = 0; nf < 4; ++nf)
        bf[nf] = *(const f16x8*)&xs_sh[xbase + nf * 16];
#pragma unroll
      for (int of = 0; of < 8; ++of)
#pragma unroll
        for (int nf = 0; nf < 4; ++nf)
          acc[of][nf] = __builtin_amdgcn_mfma_f32_16x16x32_f16(a[of], bf[nf], acc[of][nf], 0, 0, 0);
      if (hasNext) {
        ws_sh[par ^ 1][tid] = t0;
        ws_sh[par ^ 1][tid + 256] = t1;
      }
      __syncthreads();
    }
  }

  // epilogue: C/D layout col = lane&15 (pixel), row = (lane>>4)*4 + reg (o)
  const int y = y0 + w;
#pragma unroll
  for (int of = 0; of < 8; ++of) {
    const int obase = o0g + of * 16 + g * 4;
#pragma unroll
    for (int r = 0; r < 4; ++r) {
      const float bv = bias[obase + r];
      const size_t rowoff = (((size_t)b * 256 + obase + r) * 64 + y) * 64;
#pragma unroll
      for (int nf = 0; nf < 4; ++nf)
        out[rowoff + nf * 16 + ln] = acc[of][nf][r] + bv;
    }
  }
}

extern "C" void kernel_launch(void* const* d_in, const int* in_sizes, int n_in,
                              void* d_out, int out_size, void* d_ws, size_t ws_size,
                              hipStream_t stream) {
  const float* x    = (const float*)d_in[0];
  const float* pm   = (const float*)d_in[1];
  const float* bias = (const float*)d_in[2];
  float* out = (float*)d_out;
  float* ws  = (float*)d_ws;

  float* u   = ws + OFF_U;
  float* s   = ws + OFF_S;
  float* wA  = ws + OFF_WA;
  float* wB  = ws + OFF_WB;
  float* g   = ws + OFF_G;
  float* PQ  = ws + OFF_PQ;
  float* C01 = ws + OFF_C01;
  float* m   = ws + OFF_M;
  float* p3  = ws + OFF_P3;
  f16*   wcb = (f16*)(ws + OFF_G);   // alias: g is dead after Bjorck loop

  gen_u_kernel<<<3, 256, 0, stream>>>(u);
  power_kernel<<<5, 256, 0, stream>>>(pm, u, s);
  scale_kernel<<<1280, 256, 0, stream>>>(pm, s, wA);

  float* cur = wA;
  float* nxt = wB;
  for (int it = 0; it < BJORCK; ++it) {
    gram32_kernel<<<dim3(64, 5), 256, 0, stream>>>(cur, g);
    update32_kernel<<<dim3(64, 5), 256, 0, stream>>>(cur, g, nxt);
    float* tmp = cur; cur = nxt; nxt = tmp;
  }

  pq_kernel<<<dim3(16, 4), 256, 0, stream>>>(cur, PQ);
  bo_mm_kernel<<<dim3(16, 2), 256, 0, stream>>>(PQ, C01);
  bo_elem_kernel<<<256, 256, 0, stream>>>(PQ, C01, m);
  mconv_kernel<<<dim3(16, 9), 256, 0, stream>>>(m, p3);
  wT_kernel<<<dim3(16, 9), 256, 0, stream>>>(cur, p3, wcb);

  conv_mfma_kernel<<<dim3(2, 16, 16), 256, 0, stream>>>(x, wcb, bias, out);
}